// Round 6
// baseline (11408.327 us; speedup 1.0000x reference)
//
#include <hip/hip_runtime.h>

#define BDIM 256   // batch
#define SDIM 512   // seq len
#define HDIM 512   // hidden
#define VDIM 128   // vocab
#define NBG 8      // batch groups
#define BB 32      // batch per group
#define NHS 32     // hidden slices
#define HHU 16     // hidden units per block
#define KP 520     // padded LDS pitch for K=512 (bf16 elems)
#define WIHP 136   // padded pitch for W_ih slice
#define NT 320     // threads per block (5 waves)
// Static LDS pad: 61968 + 20480 = 82448 B; 2x82448 > 163840 => exactly 1 block/CU.
// Guarantees (a) co-residency of all 256 blocks (required by the producer/consumer
// protocol) and (b) no 2-per-CU packing imbalance (R4's 43.8 ms outlier dispatch).
// R0 ran fine with 145 KB static LDS, so >64 KB static is proven on this toolchain.
#define PAD_LDS 20480

typedef unsigned short ushort_t;
typedef unsigned long long u64_t;
typedef __attribute__((ext_vector_type(8))) short bf16x8;
typedef __attribute__((ext_vector_type(4))) float f32x4;

__device__ __forceinline__ ushort_t f2bf(float x) {
  unsigned u = __builtin_bit_cast(unsigned, x);
  u += 0x7fffu + ((u >> 16) & 1u);
  return (ushort_t)(u >> 16);
}
__device__ __forceinline__ float bf2f(ushort_t b) {
  unsigned u = ((unsigned)b) << 16;
  return __builtin_bit_cast(float, u);
}
__device__ __forceinline__ float sigmoidf_(float x) { return 1.f / (1.f + __expf(-x)); }
__device__ __forceinline__ float tanhf_(float x) { return 2.f / (1.f + __expf(-2.f * x)) - 1.f; }

__device__ __forceinline__ void pack_store8(ushort_t* dst, const float* s) {
  ushort_t tmp[8];
#pragma unroll
  for (int j = 0; j < 8; ++j) tmp[j] = f2bf(s[j]);
  uint4 v;
  v.x = (unsigned)tmp[0] | ((unsigned)tmp[1] << 16);
  v.y = (unsigned)tmp[2] | ((unsigned)tmp[3] << 16);
  v.z = (unsigned)tmp[4] | ((unsigned)tmp[5] << 16);
  v.w = (unsigned)tmp[6] | ((unsigned)tmp[7] << 16);
  *(uint4*)dst = v;
}

// 8 consecutive f32 -> bf16x8 fragment (same f2bf rounding as pack_store8)
__device__ __forceinline__ bf16x8 ldw8(const float* p) {
  const float4 a = *(const float4*)p;
  const float4 b = *(const float4*)(p + 4);
  bf16x8 r;
  r[0] = (short)f2bf(a.x); r[1] = (short)f2bf(a.y);
  r[2] = (short)f2bf(a.z); r[3] = (short)f2bf(a.w);
  r[4] = (short)f2bf(b.x); r[5] = (short)f2bf(b.y);
  r[6] = (short)f2bf(b.z); r[7] = (short)f2bf(b.w);
  return r;
}

// W_ih slice (one-hot gather table) + fused bias into LDS.
__device__ __forceinline__ void load_wih(ushort_t* Wih_s, float* bias_s, const float* Wih,
                                         const float* bi, const float* bh, int hs, int tid) {
  for (int c = tid; c < 64 * 16; c += NT) {  // 64 rows x 128 cols, 8-float chunks
    int r = c >> 4, k8 = (c & 15) * 8;
    int gr = (r >> 4) * HDIM + hs * HHU + (r & 15);
    pack_store8(&Wih_s[r * WIHP + k8], Wih + (size_t)gr * VDIM + k8);
  }
  if (tid < 64) {
    int gr = (tid >> 4) * HDIM + hs * HHU + (tid & 15);
    bias_s[tid] = bi[gr] + bh[gr];
  }
}

// Gate wave w (0..3): B-fragments of W_hh gate rows in registers (64 VGPR) — R4-proven.
__device__ __forceinline__ void load_whh_frag(bf16x8* wf, const float* Whh,
                                              int gate, int hs, int u, int q) {
  const size_t r = ((size_t)gate * HDIM + hs * HHU + u) * HDIM;
#pragma unroll
  for (int kt = 0; kt < 16; ++kt) wf[kt] = ldw8(Whh + r + kt * 32 + q * 8);
}

// Sync protocol: SELF-VALIDATING TAGGED DATA over the coherent LLC (agent-scope
// relaxed atomics only — the R0/R4-proven vehicle; NO flags, NO drains, NO asm).
//   hbuf element = u32: high16 = bf16(h) (exact), low16 = step tag.
//   producer (end of step t): fire-and-forget agent stores of h(t+1) tagged (t+1)
//     into buffer (t+1)&1. No vmcnt drain, no flag publish.
//   consumer (step t): load buffer t&1, per-word check tag == t; retry stale words.
//   Safety: a producer cannot start step t+1 until it consumed h(t) from ALL blocks
//   of its bg, so no block leads any other by >1 step -> buffer slot tag t can only
//   advance to t+2 after every consumer of tag-t has finished reading it. Tags make
//   partial arrival harmless (word-granular retry); u64 stores make h+tag atomic.
__global__ void __launch_bounds__(NT) lstm_kernel(
    const int* __restrict__ C_idx, const int* __restrict__ E,
    const float* __restrict__ eWih, const float* __restrict__ eWhh,
    const float* __restrict__ ebi, const float* __restrict__ ebh,
    const float* __restrict__ dWih, const float* __restrict__ dWhh,
    const float* __restrict__ dbi, const float* __restrict__ dbh,
    const float* __restrict__ pW, const float* __restrict__ pb,
    unsigned* hbuf, ushort_t* logits) {
  __shared__ ushort_t Wih_s[64 * WIHP];
  __shared__ ushort_t h_s[32 * KP];
  __shared__ float g_s[4 * BB * 17];
  __shared__ float c_s[BB * 17];
  __shared__ float bias_s[64];
  __shared__ float pb_s[4];
  __shared__ int idx_s[BB];
  __shared__ char pad_s[PAD_LDS];  // forces 1 block/CU (see #define)

  const int tid = threadIdx.x;
  const int w = tid >> 6;
  const int lane = tid & 63;
  const int bg = blockIdx.x & 7;
  const int hs = blockIdx.x >> 3;
  const int u = lane & 15, q = lane >> 4;

  if (tid == 0) *(volatile char*)pad_s = 0;  // keep pad allocated

  load_wih(Wih_s, bias_s, eWih, ebi, ebh, hs, tid);
  for (int i = tid; i < BB * 17; i += NT) c_s[i] = 0.f;

  // B-fragments in registers (R4-proven). Waves 0..3: encoder gate w. Wave 4: proj
  // rows (pW never changes; u>=4 lanes duplicate row u&3, outputs unused).
  bf16x8 wf[16];
  if (w < 4) {
    load_whh_frag(wf, eWhh, w, hs, u, q);
  } else {
    const size_t pr = (size_t)(hs * 4 + (u & 3)) * HDIM;
#pragma unroll
    for (int kt = 0; kt < 16; ++kt) wf[kt] = ldw8(pW + pr + kt * 32 + q * 8);
  }
  if (tid < 4) pb_s[tid] = pb[hs * 4 + tid];
  __syncthreads();

  for (int t = 0; t <= 1024; ++t) {
    const bool last = (t == 1024);
    if (t == 512) {  // phase switch: decoder weights (after BAR B of t=511: safe)
      load_wih(Wih_s, bias_s, dWih, dbi, dbh, hs, tid);
      if (w < 4) load_whh_frag(wf, dWhh, w, hs, u, q);
    }
    if (!last && tid < BB) {
      idx_s[tid] = (t >= 512) ? E[(size_t)(bg * BB + tid) * (SDIM + 1) + (t - 512)]
                              : C_idx[(size_t)(bg * BB + tid) * SDIM + t];
    }

    // stage h[32,512] (tagged u32, 64 KB) -> LDS bf16, validating per-word tags.
    {
      const u64_t* src = (const u64_t*)(hbuf + ((size_t)(t & 1) * BDIM + bg * BB) * HDIM);
      const unsigned tg = (unsigned)t & 0xFFFFu;
      const u64_t expect = (u64_t)tg | ((u64_t)tg << 32);
      const u64_t tmask = 0x0000FFFF0000FFFFull;
      u64_t tmp[26];
      unsigned stale = 0;
#pragma unroll
      for (int k = 0; k < 26; ++k) {
        int c = tid + k * NT;
        if (c < 8192)
          tmp[k] = __hip_atomic_load(src + c, __ATOMIC_RELAXED, __HIP_MEMORY_SCOPE_AGENT);
      }
#pragma unroll
      for (int k = 0; k < 26; ++k) {
        int c = tid + k * NT;
        if (c < 8192 && (tmp[k] & tmask) != expect) stale |= 1u << k;
      }
      int passes = 0;
      while (stale) {  // straggler words: retry only those (bounded; degrades, not hangs)
        __builtin_amdgcn_s_sleep(1);
#pragma unroll
        for (int k = 0; k < 26; ++k) {
          if ((stale >> k) & 1u) {
            int c = tid + k * NT;
            tmp[k] = __hip_atomic_load(src + c, __ATOMIC_RELAXED, __HIP_MEMORY_SCOPE_AGENT);
            if ((tmp[k] & tmask) == expect) stale &= ~(1u << k);
          }
        }
        if (++passes > (1 << 14)) break;
      }
#pragma unroll
      for (int k = 0; k < 26; ++k) {
        int c = tid + k * NT;
        if (c < 8192) {
          int r = c >> 8, col = (c & 255) * 2;  // u64 -> h elems (2c, 2c+1)
          unsigned packed = (unsigned)((tmp[k] >> 16) & 0xFFFFu) |
                            ((unsigned)(tmp[k] >> 48) << 16);
          *(unsigned*)&h_s[r * KP + col] = packed;
        }
      }
    }
    __syncthreads();  // BAR A: h_s/idx_s/weights ready

    const bool proj_on = (t >= 513);
    if ((w < 4 && !last) || (w == 4 && proj_on)) {
      f32x4 acc0 = {0.f, 0.f, 0.f, 0.f};
      f32x4 acc1 = {0.f, 0.f, 0.f, 0.f};
      if (w < 4) {
        // acc init = bias + one-hot gather from W_ih
        float bv = bias_s[w * HHU + u];
        const int rowoff = (w * HHU + u) * WIHP;
#pragma unroll
        for (int r = 0; r < 4; ++r) acc0[r] = bv + bf2f(Wih_s[rowoff + idx_s[q * 4 + r]]);
#pragma unroll
        for (int r = 0; r < 4; ++r) acc1[r] = bv + bf2f(Wih_s[rowoff + idx_s[16 + q * 4 + r]]);
      }
      const ushort_t* ap0 = &h_s[u * KP + q * 8];
      const ushort_t* ap1 = &h_s[(16 + u) * KP + q * 8];
#pragma unroll
      for (int kt = 0; kt < 16; ++kt) {
        bf16x8 af0 = *(const bf16x8*)(ap0 + kt * 32);
        bf16x8 af1 = *(const bf16x8*)(ap1 + kt * 32);
        acc0 = __builtin_amdgcn_mfma_f32_16x16x32_bf16(af0, wf[kt], acc0, 0, 0, 0);
        acc1 = __builtin_amdgcn_mfma_f32_16x16x32_bf16(af1, wf[kt], acc1, 0, 0, 0);
      }
      if (w < 4) {
#pragma unroll
        for (int r = 0; r < 4; ++r) {
          g_s[(w * BB + q * 4 + r) * 17 + u] = acc0[r];
          g_s[(w * BB + 16 + q * 4 + r) * 17 + u] = acc1[r];
        }
      } else if (u < 4) {
        const int ld = t - 513;  // logits step index 0..511
        float pbv = pb_s[u];
#pragma unroll
        for (int r = 0; r < 4; ++r) {
          logits[((size_t)ld * BDIM + bg * BB + q * 4 + r) * VDIM + hs * 4 + u] =
              f2bf(acc0[r] + pbv);
          logits[((size_t)ld * BDIM + bg * BB + 16 + q * 4 + r) * VDIM + hs * 4 + u] =
              f2bf(acc1[r] + pbv);
        }
      }
    }
    __syncthreads();  // BAR B: g_s ready; all h_s/idx_s/Wih_s reads of step t done

    if (!last && tid < 128) {  // c/h update: 32 batches x 16 units, 4 units/thread
      const int b = tid >> 2, uq = tid & 3;
      ushort_t hv[4];
#pragma unroll
      for (int j = 0; j < 4; ++j) {
        const int uu = uq * 4 + j;
        float ig = g_s[(0 * BB + b) * 17 + uu];
        float fg = g_s[(1 * BB + b) * 17 + uu];
        float gg = g_s[(2 * BB + b) * 17 + uu];
        float og = g_s[(3 * BB + b) * 17 + uu];
        float co = c_s[b * 17 + uu];
        float cn = sigmoidf_(fg) * co + sigmoidf_(ig) * tanhf_(gg);
        c_s[b * 17 + uu] = cn;
        hv[j] = f2bf(sigmoidf_(og) * tanhf_(cn));
      }
      // fire-and-forget tagged stores (h+tag atomic per u64); no drain, no flag
      const unsigned tg1 = (unsigned)(t + 1) & 0xFFFFu;
      unsigned e0 = ((unsigned)hv[0] << 16) | tg1;
      unsigned e1 = ((unsigned)hv[1] << 16) | tg1;
      unsigned e2 = ((unsigned)hv[2] << 16) | tg1;
      unsigned e3 = ((unsigned)hv[3] << 16) | tg1;
      unsigned* dstu = hbuf + ((size_t)((t + 1) & 1) * BDIM + bg * BB + b) * HDIM +
                       hs * HHU + uq * 4;
      __hip_atomic_store((u64_t*)dstu, (u64_t)e0 | ((u64_t)e1 << 32),
                         __ATOMIC_RELAXED, __HIP_MEMORY_SCOPE_AGENT);
      __hip_atomic_store((u64_t*)(dstu + 2), (u64_t)e2 | ((u64_t)e3 << 32),
                         __ATOMIC_RELAXED, __HIP_MEMORY_SCOPE_AGENT);
    }
    // no barrier here: next iteration's BAR A orders everything needed
  }
}

__global__ void loss_kernel(const ushort_t* __restrict__ logits, const int* __restrict__ E,
                            float* __restrict__ partial) {
  const int t = blockIdx.x;   // 512
  const int b = threadIdx.x;  // 256
  const ushort_t* row = logits + ((size_t)t * BDIM + b) * VDIM;
  float mx = -3.0e38f;
  for (int k = 0; k < VDIM; ++k) mx = fmaxf(mx, bf2f(row[k]));
  float se = 0.f;
  for (int k = 0; k < VDIM; ++k) se += __expf(bf2f(row[k]) - mx);
  const int tgt = E[(size_t)b * (SDIM + 1) + t];
  float nll = (mx + __logf(se)) - bf2f(row[tgt]);
  float m = (tgt != 0) ? 1.f : 0.f;
  __shared__ float s1[BDIM];
  __shared__ float s0[BDIM];
  s1[b] = nll * m;
  s0[b] = m;
  __syncthreads();
  for (int s = 128; s > 0; s >>= 1) {
    if (b < s) {
      s1[b] += s1[b + s];
      s0[b] += s0[b + s];
    }
    __syncthreads();
  }
  if (b == 0) partial[t] = (s0[0] > 0.f) ? s1[0] / s0[0] : 0.f;
}

__global__ void reduce_kernel(const float* __restrict__ partial, float* __restrict__ out) {
  __shared__ float sm[SDIM];
  sm[threadIdx.x] = partial[threadIdx.x];
  __syncthreads();
  for (int s = 256; s > 0; s >>= 1) {
    if (threadIdx.x < s) sm[threadIdx.x] += sm[threadIdx.x + s];
    __syncthreads();
  }
  if (threadIdx.x == 0) out[0] = sm[0];
}

extern "C" void kernel_launch(void* const* d_in, const int* in_sizes, int n_in,
                              void* d_out, int out_size, void* d_ws, size_t ws_size,
                              hipStream_t stream) {
  const int* C_idx = (const int*)d_in[0];
  const int* E = (const int*)d_in[1];
  const float* eWih = (const float*)d_in[2];
  const float* eWhh = (const float*)d_in[3];
  const float* ebi = (const float*)d_in[4];
  const float* ebh = (const float*)d_in[5];
  const float* dWih = (const float*)d_in[6];
  const float* dWhh = (const float*)d_in[7];
  const float* dbi = (const float*)d_in[8];
  const float* dbh = (const float*)d_in[9];
  const float* pW = (const float*)d_in[10];
  const float* pb = (const float*)d_in[11];

  char* ws = (char*)d_ws;
  unsigned* hbuf = (unsigned*)ws;                        // 2*256*512*4 = 1 MiB (tagged h)
  ushort_t* logits = (ushort_t*)(ws + 1048576);          // 512*256*128*2 = 32 MiB
  float* partial = (float*)(ws + 1048576 + 33554432);    // 512*4 B

  // zero hbuf: h(0)=0 with tag 0 (consumer at t=0 expects tag 0 in buffer 0; the
  // t&1=0 parity of buffer 1 is first read at t=1 after being fully written at t=0)
  hipMemsetAsync(d_ws, 0, 1048576, stream);
  lstm_kernel<<<256, NT, 0, stream>>>(C_idx, E, eWih, eWhh, ebi, ebh, dWih, dWhh,
                                      dbi, dbh, pW, pb, hbuf, logits);
  loss_kernel<<<512, 256, 0, stream>>>(logits, E, partial);
  reduce_kernel<<<1, 512, 0, stream>>>(partial, (float*)d_out);
}

// Round 7
// 6847.247 us; speedup vs baseline: 1.6661x; 1.6661x over previous
//
#include <hip/hip_runtime.h>

#define BDIM 256   // batch
#define SDIM 512   // seq len
#define HDIM 512   // hidden
#define VDIM 128   // vocab
#define NBG 16     // batch groups
#define BB 16      // batch per group
#define NHS 16     // hidden slices (blocks per bg)
#define HHU 32     // hidden units per block
#define KP 520     // padded LDS pitch for K=512 (bf16 elems)
#define WIHP 136   // padded pitch for W_ih slice
#define GP 33      // padded pitch for g_s/c_s (32 units + 1)
#define NT 320     // threads per block (5 waves)
// Static LDS: 62624 + PAD = 83104 B; 2x83104 > 163840 => exactly 1 block/CU.
// Co-residency of all 256 blocks is REQUIRED by the flag protocol (proven R0/R4
// property; R4's 2-per-CU packing produced a 43.8 ms outlier dispatch).
#define PAD_LDS 20480

typedef unsigned short ushort_t;
typedef unsigned long long u64_t;
typedef __attribute__((ext_vector_type(8))) short bf16x8;
typedef __attribute__((ext_vector_type(4))) float f32x4;

__device__ __forceinline__ ushort_t f2bf(float x) {
  unsigned u = __builtin_bit_cast(unsigned, x);
  u += 0x7fffu + ((u >> 16) & 1u);
  return (ushort_t)(u >> 16);
}
__device__ __forceinline__ float bf2f(ushort_t b) {
  unsigned u = ((unsigned)b) << 16;
  return __builtin_bit_cast(float, u);
}
__device__ __forceinline__ float sigmoidf_(float x) { return 1.f / (1.f + __expf(-x)); }
__device__ __forceinline__ float tanhf_(float x) { return 2.f / (1.f + __expf(-2.f * x)) - 1.f; }

__device__ __forceinline__ void pack_store8(ushort_t* dst, const float* s) {
  ushort_t tmp[8];
#pragma unroll
  for (int j = 0; j < 8; ++j) tmp[j] = f2bf(s[j]);
  uint4 v;
  v.x = (unsigned)tmp[0] | ((unsigned)tmp[1] << 16);
  v.y = (unsigned)tmp[2] | ((unsigned)tmp[3] << 16);
  v.z = (unsigned)tmp[4] | ((unsigned)tmp[5] << 16);
  v.w = (unsigned)tmp[6] | ((unsigned)tmp[7] << 16);
  *(uint4*)dst = v;
}

// 8 consecutive f32 -> bf16x8 fragment (same f2bf rounding as pack_store8)
__device__ __forceinline__ bf16x8 ldw8(const float* p) {
  const float4 a = *(const float4*)p;
  const float4 b = *(const float4*)(p + 4);
  bf16x8 r;
  r[0] = (short)f2bf(a.x); r[1] = (short)f2bf(a.y);
  r[2] = (short)f2bf(a.z); r[3] = (short)f2bf(a.w);
  r[4] = (short)f2bf(b.x); r[5] = (short)f2bf(b.y);
  r[6] = (short)f2bf(b.z); r[7] = (short)f2bf(b.w);
  return r;
}

// W_ih slice (one-hot gather table, 128 rows = 4 gates x 32 units) + fused bias.
__device__ __forceinline__ void load_wih(ushort_t* Wih_s, float* bias_s, const float* Wih,
                                         const float* bi, const float* bh, int hs, int tid) {
  for (int c = tid; c < 128 * 16; c += NT) {  // 128 rows x 128 cols, 8-float chunks
    int r = c >> 4, k8 = (c & 15) * 8;
    int gr = (r >> 5) * HDIM + hs * HHU + (r & 31);
    pack_store8(&Wih_s[r * WIHP + k8], Wih + (size_t)gr * VDIM + k8);
  }
  if (tid < 128) {
    int gr = (tid >> 5) * HDIM + hs * HHU + (tid & 31);
    bias_s[tid] = bi[gr] + bh[gr];
  }
}

// Gate wave w (0..3): B-fragments of W_hh gate-w rows for unit-tile T (T*16+u) in
// registers. Lane(u,q): fragment kt covers k = kt*32 + q*8 .. +8 (R4-proven layout).
__device__ __forceinline__ void load_whh_frag(bf16x8* wf, const float* Whh,
                                              int gate, int hs, int tile, int u, int q) {
  const size_t r = ((size_t)gate * HDIM + hs * HHU + tile * 16 + u) * HDIM;
#pragma unroll
  for (int kt = 0; kt < 16; ++kt) wf[kt] = ldw8(Whh + r + kt * 32 + q * 8);
}

// Sync protocol (per-access LLC coherence, NO cache-wide fences, NO inline asm):
//  - all cross-block data (hbuf) and flags use relaxed AGENT-scope atomics -> the
//    coherent LLC (the R0/R4-proven vehicle).
//  - producer: each of the 2 producer waves stores its 8 batches' h (relaxed),
//    then RELEASE-stores its own sub-flag (release => s_waitcnt vmcnt(0) covering
//    that wave's stores). No full-block drain barrier (R4's BAR-C deleted).
//  - consumer: w0 polls 32 sub-flags (coalesced 128B) -> barrier -> staged reads.
__global__ void __launch_bounds__(NT) lstm_kernel(
    const int* __restrict__ C_idx, const int* __restrict__ E,
    const float* __restrict__ eWih, const float* __restrict__ eWhh,
    const float* __restrict__ ebi, const float* __restrict__ ebh,
    const float* __restrict__ dWih, const float* __restrict__ dWhh,
    const float* __restrict__ dbi, const float* __restrict__ dbh,
    const float* __restrict__ pW, const float* __restrict__ pb,
    unsigned* flags, ushort_t* hbuf, ushort_t* logits) {
  __shared__ ushort_t Wih_s[128 * WIHP];
  __shared__ ushort_t h_s[16 * KP];
  __shared__ float g_s[4 * BB * GP];
  __shared__ float c_s[BB * GP];
  __shared__ float bias_s[128];
  __shared__ float pb_s[8];
  __shared__ int idx_s[BB];
  __shared__ char pad_s[PAD_LDS];  // forces 1 block/CU (see #define)

  const int tid = threadIdx.x;
  const int w = tid >> 6;
  const int lane = tid & 63;
  const int bg = blockIdx.x & 15;
  const int hs = blockIdx.x >> 4;
  const int u = lane & 15, q = lane >> 4;

  if (tid == 0) *(volatile char*)pad_s = 0;  // keep pad allocated

  load_wih(Wih_s, bias_s, eWih, ebi, ebh, hs, tid);
  for (int i = tid; i < BB * GP; i += NT) c_s[i] = 0.f;

  // B-fragments in registers. Gate waves 0..3: two unit-tiles of gate w (128 VGPR).
  // Proj wave 4: its 8 pW rows in wf0 (rows 8..15 duplicate row u&7, outputs unused);
  // pW never changes -> loaded once.
  bf16x8 wf0[16], wf1[16];
  if (w < 4) {
    load_whh_frag(wf0, eWhh, w, hs, 0, u, q);
    load_whh_frag(wf1, eWhh, w, hs, 1, u, q);
  } else {
    const size_t pr = (size_t)(hs * 8 + (u & 7)) * HDIM;
#pragma unroll
    for (int kt = 0; kt < 16; ++kt) wf0[kt] = ldw8(pW + pr + kt * 32 + q * 8);
  }
  if (tid < 8) pb_s[tid] = pb[hs * 8 + tid];
  __syncthreads();

  for (int t = 0; t <= 1024; ++t) {
    const bool last = (t == 1024);
    if (t == 512) {  // phase switch: decoder weights (after BAR-B of t=511: safe)
      load_wih(Wih_s, bias_s, dWih, dbi, dbh, hs, tid);
      if (w < 4) {
        load_whh_frag(wf0, dWhh, w, hs, 0, u, q);
        load_whh_frag(wf1, dWhh, w, hs, 1, u, q);
      }
    }
    if (!last && tid < BB) {
      idx_s[tid] = (t >= 512) ? E[(size_t)(bg * BB + tid) * (SDIM + 1) + (t - 512)]
                              : C_idx[(size_t)(bg * BB + tid) * SDIM + t];
    }
    // Wait for all 32 producer-waves (16 blocks x 2 waves) of this bg: step t-1 done.
    if (t > 0 && w == 0 && lane < 32) {
      const unsigned* fp = &flags[bg * 32 + lane];
      int spins = 0;
      while (__hip_atomic_load(fp, __ATOMIC_RELAXED, __HIP_MEMORY_SCOPE_AGENT) <
             (unsigned)t) {
        __builtin_amdgcn_s_sleep(1);
        if (++spins > (1 << 20)) break;  // deadlock bailout (never hit if co-resident)
      }
    }
    __syncthreads();  // BAR-P: h(t) known globally visible

    // stage h[16,512] bf16 (16 KB) -> LDS via LLC-coherent 8B loads
    {
      const u64_t* src = (const u64_t*)(hbuf + ((size_t)(t & 1) * BDIM + bg * BB) * HDIM);
      u64_t tmp[7];
#pragma unroll
      for (int k = 0; k < 7; ++k) {
        int c = tid + k * NT;
        if (c < 2048)
          tmp[k] = __hip_atomic_load(src + c, __ATOMIC_RELAXED, __HIP_MEMORY_SCOPE_AGENT);
      }
#pragma unroll
      for (int k = 0; k < 7; ++k) {
        int c = tid + k * NT;
        if (c < 2048) {
          int r = c >> 7, k4 = (c & 127) * 4;
          *(u64_t*)&h_s[r * KP + k4] = tmp[k];
        }
      }
    }
    __syncthreads();  // BAR-A: h_s/idx_s/weights ready

    const bool proj_on = (t >= 513);
    if ((w < 4 && !last) || (w == 4 && proj_on)) {
      f32x4 acc0 = {0.f, 0.f, 0.f, 0.f};  // unit-tile 0 (units u)      x batches q*4+r
      f32x4 acc1 = {0.f, 0.f, 0.f, 0.f};  // unit-tile 1 (units 16+u)   x batches q*4+r
      if (w < 4) {
        // acc init = bias + one-hot gather from W_ih (row = gate*32 + unit)
        const float bv0 = bias_s[w * 32 + u], bv1 = bias_s[w * 32 + 16 + u];
        const int ro0 = (w * 32 + u) * WIHP, ro1 = (w * 32 + 16 + u) * WIHP;
#pragma unroll
        for (int r = 0; r < 4; ++r) {
          const int ix = idx_s[q * 4 + r];
          acc0[r] = bv0 + bf2f(Wih_s[ro0 + ix]);
          acc1[r] = bv1 + bf2f(Wih_s[ro1 + ix]);
        }
      }
      const ushort_t* ap = &h_s[u * KP + q * 8];  // batch rows 0..15
#pragma unroll
      for (int kt = 0; kt < 16; ++kt) {
        bf16x8 af = *(const bf16x8*)(ap + kt * 32);
        acc0 = __builtin_amdgcn_mfma_f32_16x16x32_bf16(af, wf0[kt], acc0, 0, 0, 0);
        if (w < 4) acc1 = __builtin_amdgcn_mfma_f32_16x16x32_bf16(af, wf1[kt], acc1, 0, 0, 0);
      }
      if (w < 4) {
#pragma unroll
        for (int r = 0; r < 4; ++r) {
          g_s[(w * BB + q * 4 + r) * GP + u] = acc0[r];
          g_s[(w * BB + q * 4 + r) * GP + 16 + u] = acc1[r];
        }
      } else if (u < 8) {
        const int ld = t - 513;  // logits step index 0..511
        const float pbv = pb_s[u];
#pragma unroll
        for (int r = 0; r < 4; ++r) {
          logits[((size_t)ld * BDIM + bg * BB + q * 4 + r) * VDIM + hs * 8 + u] =
              f2bf(acc0[r] + pbv);
        }
      }
    }
    __syncthreads();  // BAR-B: g_s ready; all h_s/idx_s/Wih_s reads of step t done

    if (!last) {
      if (tid < 128) {  // c/h update: 16 batches x 32 units, 4 units/thread
        const int b = tid >> 3, uq = tid & 7;
        ushort_t hv[4];
#pragma unroll
        for (int j = 0; j < 4; ++j) {
          const int uu = uq * 4 + j;
          float ig = g_s[(0 * BB + b) * GP + uu];
          float fg = g_s[(1 * BB + b) * GP + uu];
          float gg = g_s[(2 * BB + b) * GP + uu];
          float og = g_s[(3 * BB + b) * GP + uu];
          float co = c_s[b * GP + uu];
          float cn = sigmoidf_(fg) * co + sigmoidf_(ig) * tanhf_(gg);
          c_s[b * GP + uu] = cn;
          hv[j] = f2bf(sigmoidf_(og) * tanhf_(cn));
        }
        u64_t pk = (u64_t)hv[0] | ((u64_t)hv[1] << 16) | ((u64_t)hv[2] << 32) |
                   ((u64_t)hv[3] << 48);
        u64_t* dst = (u64_t*)(hbuf + ((size_t)((t + 1) & 1) * BDIM + bg * BB + b) * HDIM +
                              hs * HHU + uq * 4);
        __hip_atomic_store(dst, pk, __ATOMIC_RELAXED, __HIP_MEMORY_SCOPE_AGENT);
      }
      // Per-wave release flag: waits this wave's h stores (vmcnt), then publishes.
      // No block-wide drain barrier — R4's BAR-C deleted.
      if (w < 2 && lane == 0) {
        __hip_atomic_store(&flags[bg * 32 + hs * 2 + w], (unsigned)(t + 1),
                           __ATOMIC_RELEASE, __HIP_MEMORY_SCOPE_AGENT);
      }
    }
  }
}

__global__ void loss_kernel(const ushort_t* __restrict__ logits, const int* __restrict__ E,
                            float* __restrict__ partial) {
  const int t = blockIdx.x;   // 512
  const int b = threadIdx.x;  // 256
  const ushort_t* row = logits + ((size_t)t * BDIM + b) * VDIM;
  float mx = -3.0e38f;
  for (int k = 0; k < VDIM; ++k) mx = fmaxf(mx, bf2f(row[k]));
  float se = 0.f;
  for (int k = 0; k < VDIM; ++k) se += __expf(bf2f(row[k]) - mx);
  const int tgt = E[(size_t)b * (SDIM + 1) + t];
  float nll = (mx + __logf(se)) - bf2f(row[tgt]);
  float m = (tgt != 0) ? 1.f : 0.f;
  __shared__ float s1[BDIM];
  __shared__ float s0[BDIM];
  s1[b] = nll * m;
  s0[b] = m;
  __syncthreads();
  for (int s = 128; s > 0; s >>= 1) {
    if (b < s) {
      s1[b] += s1[b + s];
      s0[b] += s0[b + s];
    }
    __syncthreads();
  }
  if (b == 0) partial[t] = (s0[0] > 0.f) ? s1[0] / s0[0] : 0.f;
}

__global__ void reduce_kernel(const float* __restrict__ partial, float* __restrict__ out) {
  __shared__ float sm[SDIM];
  sm[threadIdx.x] = partial[threadIdx.x];
  __syncthreads();
  for (int s = 256; s > 0; s >>= 1) {
    if (threadIdx.x < s) sm[threadIdx.x] += sm[threadIdx.x + s];
    __syncthreads();
  }
  if (threadIdx.x == 0) out[0] = sm[0];
}

extern "C" void kernel_launch(void* const* d_in, const int* in_sizes, int n_in,
                              void* d_out, int out_size, void* d_ws, size_t ws_size,
                              hipStream_t stream) {
  const int* C_idx = (const int*)d_in[0];
  const int* E = (const int*)d_in[1];
  const float* eWih = (const float*)d_in[2];
  const float* eWhh = (const float*)d_in[3];
  const float* ebi = (const float*)d_in[4];
  const float* ebh = (const float*)d_in[5];
  const float* dWih = (const float*)d_in[6];
  const float* dWhh = (const float*)d_in[7];
  const float* dbi = (const float*)d_in[8];
  const float* dbh = (const float*)d_in[9];
  const float* pW = (const float*)d_in[10];
  const float* pb = (const float*)d_in[11];

  char* ws = (char*)d_ws;
  unsigned* flags = (unsigned*)ws;                             // 16*32*4 B (pad to 32768)
  ushort_t* hbuf = (ushort_t*)(ws + 32768);                    // 2*256*512*2   = 524288 B
  ushort_t* logits = (ushort_t*)(ws + 32768 + 524288);         // 512*256*128*2 = 32 MiB
  float* partial = (float*)(ws + 32768 + 524288 + 33554432);   // 512*4 B

  // zero flags + h double-buffer (h0 = c0 = 0); ws is poisoned 0xAA each call
  hipMemsetAsync(d_ws, 0, 32768 + 524288, stream);
  lstm_kernel<<<256, NT, 0, stream>>>(C_idx, E, eWih, eWhh, ebi, ebh, dWih, dWhh,
                                      dbi, dbh, pW, pb, flags, hbuf, logits);
  loss_kernel<<<512, 256, 0, stream>>>(logits, E, partial);
  reduce_kernel<<<1, 512, 0, stream>>>(partial, (float*)d_out);
}

// Round 8
// 3558.123 us; speedup vs baseline: 3.2063x; 1.9244x over previous
//
#include <hip/hip_runtime.h>

#define BDIM 256   // batch
#define SDIM 512   // seq len
#define HDIM 512   // hidden
#define VDIM 128   // vocab
#define NBG 16     // batch groups
#define BB 16      // batch per group
#define NHS 16     // hidden slices (blocks per bg)
#define HHU 32     // hidden units per block
#define KP 520     // padded LDS pitch for K=512 (bf16 elems)
#define WIHP 136   // padded pitch for W_ih slice
#define GP 33      // padded pitch for g_s/c_s (32 units + 1)
#define NT 320     // threads per block (5 waves)
// Static LDS: 62624 + PAD = 83104 B; 2x83104 > 163840 => exactly 1 block/CU.
// Co-residency of all 256 blocks is REQUIRED by the flag protocol. Must be STATIC:
// the harness does not honor dynamic-LDS launch bytes (R4 evidence: LDS_Block_Size
// showed static only + a 43.8 ms 2-per-CU outlier dispatch).
#define PAD_LDS 20480

typedef unsigned short ushort_t;
typedef unsigned long long u64_t;
typedef __attribute__((ext_vector_type(8))) short bf16x8;
typedef __attribute__((ext_vector_type(4))) float f32x4;

__device__ __forceinline__ ushort_t f2bf(float x) {
  unsigned u = __builtin_bit_cast(unsigned, x);
  u += 0x7fffu + ((u >> 16) & 1u);
  return (ushort_t)(u >> 16);
}
__device__ __forceinline__ float bf2f(ushort_t b) {
  unsigned u = ((unsigned)b) << 16;
  return __builtin_bit_cast(float, u);
}
__device__ __forceinline__ float sigmoidf_(float x) { return 1.f / (1.f + __expf(-x)); }
__device__ __forceinline__ float tanhf_(float x) { return 2.f / (1.f + __expf(-2.f * x)) - 1.f; }

__device__ __forceinline__ void pack_store8(ushort_t* dst, const float* s) {
  ushort_t tmp[8];
#pragma unroll
  for (int j = 0; j < 8; ++j) tmp[j] = f2bf(s[j]);
  uint4 v;
  v.x = (unsigned)tmp[0] | ((unsigned)tmp[1] << 16);
  v.y = (unsigned)tmp[2] | ((unsigned)tmp[3] << 16);
  v.z = (unsigned)tmp[4] | ((unsigned)tmp[5] << 16);
  v.w = (unsigned)tmp[6] | ((unsigned)tmp[7] << 16);
  *(uint4*)dst = v;
}

// 8 consecutive f32 -> bf16x8 fragment (same f2bf rounding as pack_store8)
__device__ __forceinline__ bf16x8 ldw8(const float* p) {
  const float4 a = *(const float4*)p;
  const float4 b = *(const float4*)(p + 4);
  bf16x8 r;
  r[0] = (short)f2bf(a.x); r[1] = (short)f2bf(a.y);
  r[2] = (short)f2bf(a.z); r[3] = (short)f2bf(a.w);
  r[4] = (short)f2bf(b.x); r[5] = (short)f2bf(b.y);
  r[6] = (short)f2bf(b.z); r[7] = (short)f2bf(b.w);
  return r;
}

// W_ih slice (one-hot gather table, 128 rows = 4 gates x 32 units) + fused bias.
__device__ __forceinline__ void load_wih(ushort_t* Wih_s, float* bias_s, const float* Wih,
                                         const float* bi, const float* bh, int hs, int tid) {
  for (int c = tid; c < 128 * 16; c += NT) {  // 128 rows x 128 cols, 8-float chunks
    int r = c >> 4, k8 = (c & 15) * 8;
    int gr = (r >> 5) * HDIM + hs * HHU + (r & 31);
    pack_store8(&Wih_s[r * WIHP + k8], Wih + (size_t)gr * VDIM + k8);
  }
  if (tid < 128) {
    int gr = (tid >> 5) * HDIM + hs * HHU + (tid & 31);
    bias_s[tid] = bi[gr] + bh[gr];
  }
}

// Gate wave w (0..3): B-fragments of W_hh gate-w rows for unit-tile T (T*16+u) in
// registers. Lane(u,q): fragment kt covers k = kt*32 + q*8 .. +8 (R4-proven layout).
__device__ __forceinline__ void load_whh_frag(bf16x8* wf, const float* Whh,
                                              int gate, int hs, int tile, int u, int q) {
  const size_t r = ((size_t)gate * HDIM + hs * HHU + tile * 16 + u) * HDIM;
#pragma unroll
  for (int kt = 0; kt < 16; ++kt) wf[kt] = ldw8(Whh + r + kt * 32 + q * 8);
}

// Sync protocol (per-access LLC coherence, NO cache-wide fences, R0's primitives):
//  - all cross-block data (hbuf) and flags use RELAXED agent-scope atomics -> the
//    coherent LLC. NEVER acquire/release at agent scope: a release forces a
//    cache-wide writeback fence (R7: +3.2 us/step, 2x regression).
//  - producer: each of the 2 producer waves stores its h (relaxed), executes
//    s_waitcnt vmcnt(0) (wave-local drain: stores complete at the LLC -- the same
//    primitive __syncthreads uses), then RELAXED-stores its sub-flag.
//  - consumer: w0 polls 32 sub-flags (coalesced 128B) -> barrier -> staged reads.
__global__ void __launch_bounds__(NT) lstm_kernel(
    const int* __restrict__ C_idx, const int* __restrict__ E,
    const float* __restrict__ eWih, const float* __restrict__ eWhh,
    const float* __restrict__ ebi, const float* __restrict__ ebh,
    const float* __restrict__ dWih, const float* __restrict__ dWhh,
    const float* __restrict__ dbi, const float* __restrict__ dbh,
    const float* __restrict__ pW, const float* __restrict__ pb,
    unsigned* flags, ushort_t* hbuf, ushort_t* logits) {
  __shared__ ushort_t Wih_s[128 * WIHP];
  __shared__ ushort_t h_s[16 * KP];
  __shared__ float g_s[4 * BB * GP];
  __shared__ float c_s[BB * GP];
  __shared__ float bias_s[128];
  __shared__ float pb_s[8];
  __shared__ int idx_s[BB];
  __shared__ char pad_s[PAD_LDS];  // forces 1 block/CU (see #define)

  const int tid = threadIdx.x;
  const int w = tid >> 6;
  const int lane = tid & 63;
  const int bg = blockIdx.x & 15;
  const int hs = blockIdx.x >> 4;
  const int u = lane & 15, q = lane >> 4;

  if (tid == 0) *(volatile char*)pad_s = 0;  // keep pad allocated

  load_wih(Wih_s, bias_s, eWih, ebi, ebh, hs, tid);
  for (int i = tid; i < BB * GP; i += NT) c_s[i] = 0.f;

  // B-fragments in registers. Gate waves 0..3: two unit-tiles of gate w (128 VGPR).
  // Proj wave 4: its 8 pW rows in wf0 (rows 8..15 duplicate row u&7, outputs unused);
  // pW never changes -> loaded once.
  bf16x8 wf0[16], wf1[16];
  if (w < 4) {
    load_whh_frag(wf0, eWhh, w, hs, 0, u, q);
    load_whh_frag(wf1, eWhh, w, hs, 1, u, q);
  } else {
    const size_t pr = (size_t)(hs * 8 + (u & 7)) * HDIM;
#pragma unroll
    for (int kt = 0; kt < 16; ++kt) wf0[kt] = ldw8(pW + pr + kt * 32 + q * 8);
  }
  if (tid < 8) pb_s[tid] = pb[hs * 8 + tid];
  __syncthreads();

  for (int t = 0; t <= 1024; ++t) {
    const bool last = (t == 1024);
    if (t == 512) {  // phase switch: decoder weights (after BAR-B of t=511: safe)
      load_wih(Wih_s, bias_s, dWih, dbi, dbh, hs, tid);
      if (w < 4) {
        load_whh_frag(wf0, dWhh, w, hs, 0, u, q);
        load_whh_frag(wf1, dWhh, w, hs, 1, u, q);
      }
    }
    if (!last && tid < BB) {
      idx_s[tid] = (t >= 512) ? E[(size_t)(bg * BB + tid) * (SDIM + 1) + (t - 512)]
                              : C_idx[(size_t)(bg * BB + tid) * SDIM + t];
    }
    // Wait for all 32 producer-waves (16 blocks x 2 waves) of this bg: step t-1 done.
    if (t > 0 && w == 0 && lane < 32) {
      const unsigned* fp = &flags[bg * 32 + lane];
      int spins = 0;
      while (__hip_atomic_load(fp, __ATOMIC_RELAXED, __HIP_MEMORY_SCOPE_AGENT) <
             (unsigned)t) {
        __builtin_amdgcn_s_sleep(1);
        if (++spins > (1 << 20)) break;  // deadlock bailout (never hit if co-resident)
      }
    }
    __syncthreads();  // BAR-P: h(t) known globally visible

    // stage h[16,512] bf16 (16 KB) -> LDS via LLC-coherent 8B loads
    {
      const u64_t* src = (const u64_t*)(hbuf + ((size_t)(t & 1) * BDIM + bg * BB) * HDIM);
      u64_t tmp[7];
#pragma unroll
      for (int k = 0; k < 7; ++k) {
        int c = tid + k * NT;
        if (c < 2048)
          tmp[k] = __hip_atomic_load(src + c, __ATOMIC_RELAXED, __HIP_MEMORY_SCOPE_AGENT);
      }
#pragma unroll
      for (int k = 0; k < 7; ++k) {
        int c = tid + k * NT;
        if (c < 2048) {
          int r = c >> 7, k4 = (c & 127) * 4;
          *(u64_t*)&h_s[r * KP + k4] = tmp[k];
        }
      }
    }
    __syncthreads();  // BAR-A: h_s/idx_s/weights ready

    const bool proj_on = (t >= 513);
    if ((w < 4 && !last) || (w == 4 && proj_on)) {
      f32x4 acc0 = {0.f, 0.f, 0.f, 0.f};  // unit-tile 0 (units u)      x batches q*4+r
      f32x4 acc1 = {0.f, 0.f, 0.f, 0.f};  // unit-tile 1 (units 16+u)   x batches q*4+r
      if (w < 4) {
        // acc init = bias + one-hot gather from W_ih (row = gate*32 + unit)
        const float bv0 = bias_s[w * 32 + u], bv1 = bias_s[w * 32 + 16 + u];
        const int ro0 = (w * 32 + u) * WIHP, ro1 = (w * 32 + 16 + u) * WIHP;
#pragma unroll
        for (int r = 0; r < 4; ++r) {
          const int ix = idx_s[q * 4 + r];
          acc0[r] = bv0 + bf2f(Wih_s[ro0 + ix]);
          acc1[r] = bv1 + bf2f(Wih_s[ro1 + ix]);
        }
      }
      const ushort_t* ap = &h_s[u * KP + q * 8];  // batch rows 0..15
#pragma unroll
      for (int kt = 0; kt < 16; ++kt) {
        bf16x8 af = *(const bf16x8*)(ap + kt * 32);
        acc0 = __builtin_amdgcn_mfma_f32_16x16x32_bf16(af, wf0[kt], acc0, 0, 0, 0);
        if (w < 4) acc1 = __builtin_amdgcn_mfma_f32_16x16x32_bf16(af, wf1[kt], acc1, 0, 0, 0);
      }
      if (w < 4) {
#pragma unroll
        for (int r = 0; r < 4; ++r) {
          g_s[(w * BB + q * 4 + r) * GP + u] = acc0[r];
          g_s[(w * BB + q * 4 + r) * GP + 16 + u] = acc1[r];
        }
      } else if (u < 8) {
        const int ld = t - 513;  // logits step index 0..511
        const float pbv = pb_s[u];
#pragma unroll
        for (int r = 0; r < 4; ++r) {
          logits[((size_t)ld * BDIM + bg * BB + q * 4 + r) * VDIM + hs * 8 + u] =
              f2bf(acc0[r] + pbv);
        }
      }
    }
    __syncthreads();  // BAR-B: g_s ready; all h_s/idx_s/Wih_s reads of step t done

    if (!last) {
      if (tid < 128) {  // c/h update: 16 batches x 32 units, 4 units/thread
        const int b = tid >> 3, uq = tid & 7;
        ushort_t hv[4];
#pragma unroll
        for (int j = 0; j < 4; ++j) {
          const int uu = uq * 4 + j;
          float ig = g_s[(0 * BB + b) * GP + uu];
          float fg = g_s[(1 * BB + b) * GP + uu];
          float gg = g_s[(2 * BB + b) * GP + uu];
          float og = g_s[(3 * BB + b) * GP + uu];
          float co = c_s[b * GP + uu];
          float cn = sigmoidf_(fg) * co + sigmoidf_(ig) * tanhf_(gg);
          c_s[b * GP + uu] = cn;
          hv[j] = f2bf(sigmoidf_(og) * tanhf_(cn));
        }
        u64_t pk = (u64_t)hv[0] | ((u64_t)hv[1] << 16) | ((u64_t)hv[2] << 32) |
                   ((u64_t)hv[3] << 48);
        u64_t* dst = (u64_t*)(hbuf + ((size_t)((t + 1) & 1) * BDIM + bg * BB + b) * HDIM +
                              hs * HHU + uq * 4);
        __hip_atomic_store(dst, pk, __ATOMIC_RELAXED, __HIP_MEMORY_SCOPE_AGENT);
      }
      // Per-wave ordered publish: drain THIS wave's h stores to the LLC (wave-local
      // s_waitcnt, no cache-wide fence -- R0's exact ordering primitive, per-wave),
      // then RELAXED flag store. R7's __ATOMIC_RELEASE here cost 2x: cache-wide
      // writeback fence per wave per step.
      if (w < 2) {
        asm volatile("s_waitcnt vmcnt(0)" ::: "memory");
        if (lane == 0)
          __hip_atomic_store(&flags[bg * 32 + hs * 2 + w], (unsigned)(t + 1),
                             __ATOMIC_RELAXED, __HIP_MEMORY_SCOPE_AGENT);
      }
    }
  }
}

__global__ void loss_kernel(const ushort_t* __restrict__ logits, const int* __restrict__ E,
                            float* __restrict__ partial) {
  const int t = blockIdx.x;   // 512
  const int b = threadIdx.x;  // 256
  const ushort_t* row = logits + ((size_t)t * BDIM + b) * VDIM;
  float mx = -3.0e38f;
  for (int k = 0; k < VDIM; ++k) mx = fmaxf(mx, bf2f(row[k]));
  float se = 0.f;
  for (int k = 0; k < VDIM; ++k) se += __expf(bf2f(row[k]) - mx);
  const int tgt = E[(size_t)b * (SDIM + 1) + t];
  float nll = (mx + __logf(se)) - bf2f(row[tgt]);
  float m = (tgt != 0) ? 1.f : 0.f;
  __shared__ float s1[BDIM];
  __shared__ float s0[BDIM];
  s1[b] = nll * m;
  s0[b] = m;
  __syncthreads();
  for (int s = 128; s > 0; s >>= 1) {
    if (b < s) {
      s1[b] += s1[b + s];
      s0[b] += s0[b + s];
    }
    __syncthreads();
  }
  if (b == 0) partial[t] = (s0[0] > 0.f) ? s1[0] / s0[0] : 0.f;
}

__global__ void reduce_kernel(const float* __restrict__ partial, float* __restrict__ out) {
  __shared__ float sm[SDIM];
  sm[threadIdx.x] = partial[threadIdx.x];
  __syncthreads();
  for (int s = 256; s > 0; s >>= 1) {
    if (threadIdx.x < s) sm[threadIdx.x] += sm[threadIdx.x + s];
    __syncthreads();
  }
  if (threadIdx.x == 0) out[0] = sm[0];
}

extern "C" void kernel_launch(void* const* d_in, const int* in_sizes, int n_in,
                              void* d_out, int out_size, void* d_ws, size_t ws_size,
                              hipStream_t stream) {
  const int* C_idx = (const int*)d_in[0];
  const int* E = (const int*)d_in[1];
  const float* eWih = (const float*)d_in[2];
  const float* eWhh = (const float*)d_in[3];
  const float* ebi = (const float*)d_in[4];
  const float* ebh = (const float*)d_in[5];
  const float* dWih = (const float*)d_in[6];
  const float* dWhh = (const float*)d_in[7];
  const float* dbi = (const float*)d_in[8];
  const float* dbh = (const float*)d_in[9];
  const float* pW = (const float*)d_in[10];
  const float* pb = (const float*)d_in[11];

  char* ws = (char*)d_ws;
  unsigned* flags = (unsigned*)ws;                             // 16*32*4 B (pad to 32768)
  ushort_t* hbuf = (ushort_t*)(ws + 32768);                    // 2*256*512*2   = 524288 B
  ushort_t* logits = (ushort_t*)(ws + 32768 + 524288);         // 512*256*128*2 = 32 MiB
  float* partial = (float*)(ws + 32768 + 524288 + 33554432);   // 512*4 B

  // zero flags + h double-buffer (h0 = c0 = 0); ws is poisoned 0xAA each call
  hipMemsetAsync(d_ws, 0, 32768 + 524288, stream);
  lstm_kernel<<<256, NT, 0, stream>>>(C_idx, E, eWih, eWhh, ebi, ebh, dWih, dWhh,
                                      dbi, dbh, pW, pb, flags, hbuf, logits);
  loss_kernel<<<512, 256, 0, stream>>>(logits, E, partial);
  reduce_kernel<<<1, 512, 0, stream>>>(partial, (float*)d_out);
}

// Round 9
// 3446.244 us; speedup vs baseline: 3.3104x; 1.0325x over previous
//
#include <hip/hip_runtime.h>

#define BDIM 256   // batch
#define SDIM 512   // seq len
#define HDIM 512   // hidden
#define VDIM 128   // vocab
#define NBG 16     // batch groups
#define BB 16      // batch per group
#define NHS 16     // hidden slices (blocks per bg)
#define HHU 32     // hidden units per block
#define KP 520     // padded LDS pitch for K=512 (bf16 elems)
#define WIHP 136   // padded pitch for W_ih slice
#define GP 33      // padded pitch for g_s/c_s (32 units + 1)
#define NT 320     // threads per block (5 waves)
// Static LDS: 62624 + PAD = 83104 B; 2x83104 > 163840 => exactly 1 block/CU.
// Co-residency of all 256 blocks is REQUIRED by the flag protocol. Must be STATIC
// (dynamic-LDS launch bytes are not honored by the harness — R4 evidence).
#define PAD_LDS 20480

typedef unsigned short ushort_t;
typedef unsigned long long u64_t;
typedef __attribute__((ext_vector_type(8))) short bf16x8;
typedef __attribute__((ext_vector_type(4))) float f32x4;

__device__ __forceinline__ ushort_t f2bf(float x) {
  unsigned u = __builtin_bit_cast(unsigned, x);
  u += 0x7fffu + ((u >> 16) & 1u);
  return (ushort_t)(u >> 16);
}
__device__ __forceinline__ float bf2f(ushort_t b) {
  unsigned u = ((unsigned)b) << 16;
  return __builtin_bit_cast(float, u);
}
__device__ __forceinline__ float sigmoidf_(float x) { return 1.f / (1.f + __expf(-x)); }
__device__ __forceinline__ float tanhf_(float x) { return 2.f / (1.f + __expf(-2.f * x)) - 1.f; }

__device__ __forceinline__ void pack_store8(ushort_t* dst, const float* s) {
  ushort_t tmp[8];
#pragma unroll
  for (int j = 0; j < 8; ++j) tmp[j] = f2bf(s[j]);
  uint4 v;
  v.x = (unsigned)tmp[0] | ((unsigned)tmp[1] << 16);
  v.y = (unsigned)tmp[2] | ((unsigned)tmp[3] << 16);
  v.z = (unsigned)tmp[4] | ((unsigned)tmp[5] << 16);
  v.w = (unsigned)tmp[6] | ((unsigned)tmp[7] << 16);
  *(uint4*)dst = v;
}

// 8 consecutive f32 -> bf16x8 fragment (same f2bf rounding as pack_store8)
__device__ __forceinline__ bf16x8 ldw8(const float* p) {
  const float4 a = *(const float4*)p;
  const float4 b = *(const float4*)(p + 4);
  bf16x8 r;
  r[0] = (short)f2bf(a.x); r[1] = (short)f2bf(a.y);
  r[2] = (short)f2bf(a.z); r[3] = (short)f2bf(a.w);
  r[4] = (short)f2bf(b.x); r[5] = (short)f2bf(b.y);
  r[6] = (short)f2bf(b.z); r[7] = (short)f2bf(b.w);
  return r;
}

// W_ih slice (one-hot gather table, 128 rows = 4 gates x 32 units) + fused bias.
__device__ __forceinline__ void load_wih(ushort_t* Wih_s, float* bias_s, const float* Wih,
                                         const float* bi, const float* bh, int hs, int tid) {
  for (int c = tid; c < 128 * 16; c += NT) {  // 128 rows x 128 cols, 8-float chunks
    int r = c >> 4, k8 = (c & 15) * 8;
    int gr = (r >> 5) * HDIM + hs * HHU + (r & 31);
    pack_store8(&Wih_s[r * WIHP + k8], Wih + (size_t)gr * VDIM + k8);
  }
  if (tid < 128) {
    int gr = (tid >> 5) * HDIM + hs * HHU + (tid & 31);
    bias_s[tid] = bi[gr] + bh[gr];
  }
}

// Gate wave w (0..3): B-fragments of W_hh gate-w rows for unit-tile T (T*16+u) in
// registers. Lane(u,q): fragment kt covers k = kt*32 + q*8 .. +8 (R4-proven layout).
__device__ __forceinline__ void load_whh_frag(bf16x8* wf, const float* Whh,
                                              int gate, int hs, int tile, int u, int q) {
  const size_t r = ((size_t)gate * HDIM + hs * HHU + tile * 16 + u) * HDIM;
#pragma unroll
  for (int kt = 0; kt < 16; ++kt) wf[kt] = ldw8(Whh + r + kt * 32 + q * 8);
}

// Sync protocol (per-access LLC coherence, NO cache-wide fences, R0's primitives):
//  - cross-block h and flags are published via FIRE-AND-FORGET ATOMIC SWAPS
//    (result discarded -> non-returning global_atomic_swap[_x2]). Atomics execute
//    AT the LLC: the line is dirtied in the LLC (no HBM write-through) and the
//    vmcnt ack returns from the LLC, not HBM. R8's plain agent stores showed
//    WRITE_SIZE == full h traffic (311 MB) = write-through; this removes it.
//  - ordering: relaxed swaps -> s_waitcnt vmcnt(0) (wave-local drain, atomics
//    count in vmcnt) -> relaxed flag swap. NEVER acquire/release at agent scope
//    (R7: cache-wide writeback fence, 2x regression).
//  - consumer: w0 polls 32 sub-flags (coalesced 128B relaxed load) -> barrier ->
//    relaxed staged loads (served by LLC).
__global__ void __launch_bounds__(NT) lstm_kernel(
    const int* __restrict__ C_idx, const int* __restrict__ E,
    const float* __restrict__ eWih, const float* __restrict__ eWhh,
    const float* __restrict__ ebi, const float* __restrict__ ebh,
    const float* __restrict__ dWih, const float* __restrict__ dWhh,
    const float* __restrict__ dbi, const float* __restrict__ dbh,
    const float* __restrict__ pW, const float* __restrict__ pb,
    unsigned* flags, ushort_t* hbuf, ushort_t* logits) {
  __shared__ ushort_t Wih_s[128 * WIHP];
  __shared__ ushort_t h_s[16 * KP];
  __shared__ float g_s[4 * BB * GP];
  __shared__ float c_s[BB * GP];
  __shared__ float bias_s[128];
  __shared__ float pb_s[8];
  __shared__ int idx_s[BB];
  __shared__ char pad_s[PAD_LDS];  // forces 1 block/CU (see #define)

  const int tid = threadIdx.x;
  const int w = tid >> 6;
  const int lane = tid & 63;
  const int bg = blockIdx.x & 15;
  const int hs = blockIdx.x >> 4;
  const int u = lane & 15, q = lane >> 4;

  if (tid == 0) *(volatile char*)pad_s = 0;  // keep pad allocated

  load_wih(Wih_s, bias_s, eWih, ebi, ebh, hs, tid);
  for (int i = tid; i < BB * GP; i += NT) c_s[i] = 0.f;

  // B-fragments in registers. Gate waves 0..3: two unit-tiles of gate w (128 VGPR).
  // Proj wave 4: its 8 pW rows in wf0 (rows 8..15 duplicate row u&7, outputs unused);
  // pW never changes -> loaded once.
  bf16x8 wf0[16], wf1[16];
  if (w < 4) {
    load_whh_frag(wf0, eWhh, w, hs, 0, u, q);
    load_whh_frag(wf1, eWhh, w, hs, 1, u, q);
  } else {
    const size_t pr = (size_t)(hs * 8 + (u & 7)) * HDIM;
#pragma unroll
    for (int kt = 0; kt < 16; ++kt) wf0[kt] = ldw8(pW + pr + kt * 32 + q * 8);
  }
  if (tid < 8) pb_s[tid] = pb[hs * 8 + tid];
  __syncthreads();

  for (int t = 0; t <= 1024; ++t) {
    const bool last = (t == 1024);
    if (t == 512) {  // phase switch: decoder weights (after BAR-B of t=511: safe)
      load_wih(Wih_s, bias_s, dWih, dbi, dbh, hs, tid);
      if (w < 4) {
        load_whh_frag(wf0, dWhh, w, hs, 0, u, q);
        load_whh_frag(wf1, dWhh, w, hs, 1, u, q);
      }
    }
    if (!last && tid < BB) {
      idx_s[tid] = (t >= 512) ? E[(size_t)(bg * BB + tid) * (SDIM + 1) + (t - 512)]
                              : C_idx[(size_t)(bg * BB + tid) * SDIM + t];
    }
    // Wait for all 32 producer-waves (16 blocks x 2 waves) of this bg: step t-1 done.
    if (t > 0 && w == 0 && lane < 32) {
      const unsigned* fp = &flags[bg * 32 + lane];
      int spins = 0;
      while (__hip_atomic_load(fp, __ATOMIC_RELAXED, __HIP_MEMORY_SCOPE_AGENT) <
             (unsigned)t) {
        __builtin_amdgcn_s_sleep(1);
        if (++spins > (1 << 20)) break;  // deadlock bailout (never hit if co-resident)
      }
    }
    __syncthreads();  // BAR-P: h(t) known globally visible

    // stage h[16,512] bf16 (16 KB) -> LDS via LLC-coherent 8B loads
    {
      const u64_t* src = (const u64_t*)(hbuf + ((size_t)(t & 1) * BDIM + bg * BB) * HDIM);
      u64_t tmp[7];
#pragma unroll
      for (int k = 0; k < 7; ++k) {
        int c = tid + k * NT;
        if (c < 2048)
          tmp[k] = __hip_atomic_load(src + c, __ATOMIC_RELAXED, __HIP_MEMORY_SCOPE_AGENT);
      }
#pragma unroll
      for (int k = 0; k < 7; ++k) {
        int c = tid + k * NT;
        if (c < 2048) {
          int r = c >> 7, k4 = (c & 127) * 4;
          *(u64_t*)&h_s[r * KP + k4] = tmp[k];
        }
      }
    }
    __syncthreads();  // BAR-A: h_s/idx_s/weights ready

    const bool proj_on = (t >= 513);
    if ((w < 4 && !last) || (w == 4 && proj_on)) {
      f32x4 acc0 = {0.f, 0.f, 0.f, 0.f};  // unit-tile 0 (units u)      x batches q*4+r
      f32x4 acc1 = {0.f, 0.f, 0.f, 0.f};  // unit-tile 1 (units 16+u)   x batches q*4+r
      if (w < 4) {
        // acc init = bias + one-hot gather from W_ih (row = gate*32 + unit)
        const float bv0 = bias_s[w * 32 + u], bv1 = bias_s[w * 32 + 16 + u];
        const int ro0 = (w * 32 + u) * WIHP, ro1 = (w * 32 + 16 + u) * WIHP;
#pragma unroll
        for (int r = 0; r < 4; ++r) {
          const int ix = idx_s[q * 4 + r];
          acc0[r] = bv0 + bf2f(Wih_s[ro0 + ix]);
          acc1[r] = bv1 + bf2f(Wih_s[ro1 + ix]);
        }
      }
      const ushort_t* ap = &h_s[u * KP + q * 8];  // batch rows 0..15
#pragma unroll
      for (int kt = 0; kt < 16; ++kt) {
        bf16x8 af = *(const bf16x8*)(ap + kt * 32);
        acc0 = __builtin_amdgcn_mfma_f32_16x16x32_bf16(af, wf0[kt], acc0, 0, 0, 0);
        if (w < 4) acc1 = __builtin_amdgcn_mfma_f32_16x16x32_bf16(af, wf1[kt], acc1, 0, 0, 0);
      }
      if (w < 4) {
#pragma unroll
        for (int r = 0; r < 4; ++r) {
          g_s[(w * BB + q * 4 + r) * GP + u] = acc0[r];
          g_s[(w * BB + q * 4 + r) * GP + 16 + u] = acc1[r];
        }
      } else if (u < 8) {
        const int ld = t - 513;  // logits step index 0..511
        const float pbv = pb_s[u];
#pragma unroll
        for (int r = 0; r < 4; ++r) {
          logits[((size_t)ld * BDIM + bg * BB + q * 4 + r) * VDIM + hs * 8 + u] =
              f2bf(acc0[r] + pbv);
        }
      }
    }
    __syncthreads();  // BAR-B: g_s ready; all h_s/idx_s/Wih_s reads of step t done

    if (!last) {
      if (tid < 128) {  // c/h update: 16 batches x 32 units, 4 units/thread
        const int b = tid >> 3, uq = tid & 7;
        ushort_t hv[4];
#pragma unroll
        for (int j = 0; j < 4; ++j) {
          const int uu = uq * 4 + j;
          float ig = g_s[(0 * BB + b) * GP + uu];
          float fg = g_s[(1 * BB + b) * GP + uu];
          float gg = g_s[(2 * BB + b) * GP + uu];
          float og = g_s[(3 * BB + b) * GP + uu];
          float co = c_s[b * GP + uu];
          float cn = sigmoidf_(fg) * co + sigmoidf_(ig) * tanhf_(gg);
          c_s[b * GP + uu] = cn;
          hv[j] = f2bf(sigmoidf_(og) * tanhf_(cn));
        }
        u64_t pk = (u64_t)hv[0] | ((u64_t)hv[1] << 16) | ((u64_t)hv[2] << 32) |
                   ((u64_t)hv[3] << 48);
        u64_t* dst = (u64_t*)(hbuf + ((size_t)((t + 1) & 1) * BDIM + bg * BB + b) * HDIM +
                              hs * HHU + uq * 4);
        // fire-and-forget swap: executes AT the LLC, dirties the line there
        // (no HBM write-through), vmcnt ack from LLC.
        (void)__hip_atomic_exchange(dst, pk, __ATOMIC_RELAXED, __HIP_MEMORY_SCOPE_AGENT);
      }
      // Per-wave ordered publish: drain THIS wave's h swaps (wave-local vmcnt, no
      // cache-wide fence), then relaxed flag swap.
      if (w < 2) {
        asm volatile("s_waitcnt vmcnt(0)" ::: "memory");
        if (lane == 0)
          (void)__hip_atomic_exchange(&flags[bg * 32 + hs * 2 + w], (unsigned)(t + 1),
                                      __ATOMIC_RELAXED, __HIP_MEMORY_SCOPE_AGENT);
      }
    }
  }
}

__global__ void loss_kernel(const ushort_t* __restrict__ logits, const int* __restrict__ E,
                            float* __restrict__ partial) {
  const int t = blockIdx.x;   // 512
  const int b = threadIdx.x;  // 256
  const ushort_t* row = logits + ((size_t)t * BDIM + b) * VDIM;
  float mx = -3.0e38f;
  for (int k = 0; k < VDIM; ++k) mx = fmaxf(mx, bf2f(row[k]));
  float se = 0.f;
  for (int k = 0; k < VDIM; ++k) se += __expf(bf2f(row[k]) - mx);
  const int tgt = E[(size_t)b * (SDIM + 1) + t];
  float nll = (mx + __logf(se)) - bf2f(row[tgt]);
  float m = (tgt != 0) ? 1.f : 0.f;
  __shared__ float s1[BDIM];
  __shared__ float s0[BDIM];
  s1[b] = nll * m;
  s0[b] = m;
  __syncthreads();
  for (int s = 128; s > 0; s >>= 1) {
    if (b < s) {
      s1[b] += s1[b + s];
      s0[b] += s0[b + s];
    }
    __syncthreads();
  }
  if (b == 0) partial[t] = (s0[0] > 0.f) ? s1[0] / s0[0] : 0.f;
}

__global__ void reduce_kernel(const float* __restrict__ partial, float* __restrict__ out) {
  __shared__ float sm[SDIM];
  sm[threadIdx.x] = partial[threadIdx.x];
  __syncthreads();
  for (int s = 256; s > 0; s >>= 1) {
    if (threadIdx.x < s) sm[threadIdx.x] += sm[threadIdx.x + s];
    __syncthreads();
  }
  if (threadIdx.x == 0) out[0] = sm[0];
}

extern "C" void kernel_launch(void* const* d_in, const int* in_sizes, int n_in,
                              void* d_out, int out_size, void* d_ws, size_t ws_size,
                              hipStream_t stream) {
  const int* C_idx = (const int*)d_in[0];
  const int* E = (const int*)d_in[1];
  const float* eWih = (const float*)d_in[2];
  const float* eWhh = (const float*)d_in[3];
  const float* ebi = (const float*)d_in[4];
  const float* ebh = (const float*)d_in[5];
  const float* dWih = (const float*)d_in[6];
  const float* dWhh = (const float*)d_in[7];
  const float* dbi = (const float*)d_in[8];
  const float* dbh = (const float*)d_in[9];
  const float* pW = (const float*)d_in[10];
  const float* pb = (const float*)d_in[11];

  char* ws = (char*)d_ws;
  unsigned* flags = (unsigned*)ws;                             // 16*32*4 B (pad to 32768)
  ushort_t* hbuf = (ushort_t*)(ws + 32768);                    // 2*256*512*2   = 524288 B
  ushort_t* logits = (ushort_t*)(ws + 32768 + 524288);         // 512*256*128*2 = 32 MiB
  float* partial = (float*)(ws + 32768 + 524288 + 33554432);   // 512*4 B

  // zero flags + h double-buffer (h0 = c0 = 0); ws is poisoned 0xAA each call
  hipMemsetAsync(d_ws, 0, 32768 + 524288, stream);
  lstm_kernel<<<256, NT, 0, stream>>>(C_idx, E, eWih, eWhh, ebi, ebh, dWih, dWhh,
                                      dbi, dbh, pW, pb, flags, hbuf, logits);
  loss_kernel<<<512, 256, 0, stream>>>(logits, E, partial);
  reduce_kernel<<<1, 512, 0, stream>>>(partial, (float*)d_out);
}